// Round 4
// baseline (140.121 us; speedup 1.0000x reference)
//
#include <hip/hip_runtime.h>
#include <hip/hip_fp16.h>
#include <cmath>

#define NBINS   84
#define NFRAMES 256
#define HOP     1024
#define NB      8            // nb_samples * nb_channels
#define KP      960          // padded K (columns of A / rows of B)
#define GBLK    278          // number of 1024-sample output blocks
#define MROWS   (GBLK*NB)    // 2224 real rows
#define MPAD    2240         // 35*64
#define NRROWS  45           // distinct norm rows: g in [0,22) | interior | (255,278)

typedef _Float16 f16x8 __attribute__((ext_vector_type(8)));
typedef float    f32x4 __attribute__((ext_vector_type(4)));

struct CqtArgs {
    int   wl[NBINS];     // per-bin window length
    int   cb[NBINS];     // column base: prefix sum of 2*ceil(wl/1024)
    float omega[NBINS];  // 2*pi*f/SR
    float invL[NBINS];   // 1/wl
    int   Ktot;
};

// col -> (k, d, c) lookup table; rec = k | d<<8 | c<<16, k=0xFF invalid/pad
__global__ void build_coltab(int* __restrict__ ct, CqtArgs a) {
    int col = blockIdx.x * 256 + threadIdx.x;
    if (col >= KP) return;
    int rec = 0xFF;
    if (col < a.Ktot) {
        for (int k = 0; k < NBINS; ++k) {
            int D2 = (((a.wl[k] + 1023) >> 10) << 1);
            int j  = col - a.cb[k];
            if (j >= 0 && j < D2) { rec = k | ((j >> 1) << 8) | ((j & 1) << 16); break; }
        }
    }
    ct[col] = rec;
}

// Bt[r][col] = (c ? sin : cos)(omega_k * t) * hann(t),  t = 1024 d + r, 0 if t >= L
__global__ void build_Bt(unsigned short* __restrict__ Bt, const int* __restrict__ ct,
                         CqtArgs a) {
    int col = blockIdx.x * 256 + threadIdx.x;
    int r   = blockIdx.y;
    if (col >= KP) return;
    float val = 0.f;
    int rec = ct[col];
    int k = rec & 0xFF;
    if (k != 0xFF) {
        int d = (rec >> 8) & 0xFF, c = rec >> 16;
        int t = (d << 10) + r;
        if (t < a.wl[k]) {
            float tf  = (float)t;
            float w   = 0.5f - 0.5f * cosf(6.28318530717958647692f * tf * a.invL[k]);
            float ang = a.omega[k] * tf;
            val = (c ? sinf(ang) : cosf(ang)) * w;
        }
    }
    Bt[(size_t)r * KP + col] = __half_as_ushort(__float2half(val));
}

// A[row=(g*8+b)][col=(k,d,c)] = c==0 ? Re X[b,k,g-d] : -Im X[b,k,g-d]; 0 OOB/pad
__global__ void build_A(unsigned short* __restrict__ Am, const float* __restrict__ X,
                        const int* __restrict__ ct, CqtArgs a) {
    int col = blockIdx.x * 256 + threadIdx.x;
    int row = blockIdx.y;
    if (col >= KP) return;
    float val = 0.f;
    int rec = ct[col];
    int k = rec & 0xFF;
    if (row < MROWS && k != 0xFF) {
        int d = (rec >> 8) & 0xFF, c = rec >> 16;
        int g = row >> 3, b = row & 7;
        int f = g - d;
        if (f >= 0 && f < NFRAMES) {
            float x = X[(((size_t)b * NBINS + k) * NFRAMES + f) * 2 + c];
            val = c ? -x : x;
        }
    }
    Am[(size_t)row * KP + col] = __half_as_ushort(__float2half(val));
}

// 45 distinct inverse-norm rows (f32, trig-exact): g<22 -> row g; interior -> 22;
// g in (255,278) -> row g-233.
__global__ void build_normrows(float* __restrict__ NR, CqtArgs a) {
    int r    = blockIdx.x * 256 + threadIdx.x;
    int grow = blockIdx.y;
    if (r >= 1024) return;
    int g = grow < 22 ? grow : (grow == 22 ? 128 : 233 + grow);
    float n = 0.f;
    for (int k = 0; k < NBINS; ++k) {
        int L = a.wl[k];
        int D = (L + 1023) >> 10;
        for (int d = 0; d < D; ++d) {
            int f = g - d;
            if (f < 0) break;
            if (f >= NFRAMES) continue;
            int t = (d << 10) + r;
            if (t < L) {
                float w = 0.5f - 0.5f * cosf(6.28318530717958647692f * (float)t * a.invL[k]);
                n += w * w;
            }
        }
    }
    NR[grow * 1024 + r] = (n > 1e-10f) ? (1.0f / n) : 1.0f;
}

// GEMM: C[M=2240][N=1024] = A[M][K=960] * Bt[N][K]^T, f16 in / f32 acc.
// 64x64 tile, 4 waves (2x2), each wave 32x32 via 2x2 mfma_f32_16x16x32_f16.
// LDS [row][kchunk] with chunk-XOR swizzle (T2); next-K global loads overlap MFMA.
__global__ __launch_bounds__(256)
void gemm_icqt(const unsigned short* __restrict__ Am, const unsigned short* __restrict__ Bt,
               const float* __restrict__ NR, float* __restrict__ out, int length) {
    __shared__ __align__(16) char lds[16384];
    const int tid = threadIdx.x;
    const int l   = tid & 63;
    const int wid = tid >> 6;
    const int wm  = wid >> 1, wn = wid & 1;
    const int bm  = blockIdx.x, bn = blockIdx.y;

    // staging: 512 16B-chunks per 64x64 f16 tile; thread covers q0=tid, q1=tid+256
    const int q0 = tid,      q1 = tid + 256;
    const int r0 = q0 >> 3,  c0 = q0 & 7, s0 = c0 ^ (r0 & 7);
    const int r1 = q1 >> 3,  c1 = q1 & 7, s1 = c1 ^ (r1 & 7);

    const char* gA = (const char*)Am + (size_t)(bm * 64) * KP * 2;
    const char* gB = (const char*)Bt + (size_t)(bn * 64) * KP * 2;
    const char* gA0 = gA + ((size_t)r0 * KP + s0 * 8) * 2;
    const char* gA1 = gA + ((size_t)r1 * KP + s1 * 8) * 2;
    const char* gB0 = gB + ((size_t)r0 * KP + s0 * 8) * 2;
    const char* gB1 = gB + ((size_t)r1 * KP + s1 * 8) * 2;
    char* lA = lds;
    char* lB = lds + 8192;

    f32x4 acc00 = {0.f,0.f,0.f,0.f}, acc01 = {0.f,0.f,0.f,0.f};
    f32x4 acc10 = {0.f,0.f,0.f,0.f}, acc11 = {0.f,0.f,0.f,0.f};

    f16x8 ra0 = *(const f16x8*)(gA0);
    f16x8 ra1 = *(const f16x8*)(gA1);
    f16x8 rb0 = *(const f16x8*)(gB0);
    f16x8 rb1 = *(const f16x8*)(gB1);

    const int arow0 = wm * 32 + (l & 15), arow1 = arow0 + 16;
    const int brow0 = wn * 32 + (l & 15), brow1 = brow0 + 16;
    const int kq = l >> 4;   // 0..3: k-chunk sub-index

    for (int kk = 0; kk < KP; kk += 64) {
        __syncthreads();                     // previous frag reads complete
        *(f16x8*)(lA + q0 * 16) = ra0;
        *(f16x8*)(lA + q1 * 16) = ra1;
        *(f16x8*)(lB + q0 * 16) = rb0;
        *(f16x8*)(lB + q1 * 16) = rb1;
        __syncthreads();
        if (kk + 64 < KP) {                  // prefetch next K-panel (overlaps MFMA)
            ra0 = *(const f16x8*)(gA0 + (kk + 64) * 2);
            ra1 = *(const f16x8*)(gA1 + (kk + 64) * 2);
            rb0 = *(const f16x8*)(gB0 + (kk + 64) * 2);
            rb1 = *(const f16x8*)(gB1 + (kk + 64) * 2);
        }
#pragma unroll
        for (int ks = 0; ks < 2; ++ks) {
            const int kb = ks * 4 + kq;      // chunk 0..7 within row
            f16x8 a0 = *(const f16x8*)(lA + arow0 * 128 + ((kb ^ (arow0 & 7)) << 4));
            f16x8 a1 = *(const f16x8*)(lA + arow1 * 128 + ((kb ^ (arow1 & 7)) << 4));
            f16x8 b0 = *(const f16x8*)(lB + brow0 * 128 + ((kb ^ (brow0 & 7)) << 4));
            f16x8 b1 = *(const f16x8*)(lB + brow1 * 128 + ((kb ^ (brow1 & 7)) << 4));
            acc00 = __builtin_amdgcn_mfma_f32_16x16x32_f16(a0, b0, acc00, 0, 0, 0);
            acc01 = __builtin_amdgcn_mfma_f32_16x16x32_f16(a0, b1, acc01, 0, 0, 0);
            acc10 = __builtin_amdgcn_mfma_f32_16x16x32_f16(a1, b0, acc10, 0, 0, 0);
            acc11 = __builtin_amdgcn_mfma_f32_16x16x32_f16(a1, b1, acc11, 0, 0, 0);
        }
    }

    // epilogue: C/D layout col=l&15, row=(l>>4)*4+reg; divide by norm, scatter to out
    const int mbase = bm * 64 + wm * 32;
    const int nbase = bn * 64 + wn * 32;
#pragma unroll
    for (int mi = 0; mi < 2; ++mi) {
#pragma unroll
        for (int ni = 0; ni < 2; ++ni) {
            f32x4 v = (mi == 0) ? ((ni == 0) ? acc00 : acc01)
                                : ((ni == 0) ? acc10 : acc11);
            const int ncol = nbase + ni * 16 + (l & 15);
#pragma unroll
            for (int reg = 0; reg < 4; ++reg) {
                const int mrow = mbase + mi * 16 + (l >> 4) * 4 + reg;
                if (mrow < MROWS) {
                    const int g = mrow >> 3, b = mrow & 7;
                    const int p = (g << 10) + ncol;
                    if (p < length) {
                        const int grow = (g < 22) ? g : ((g <= 255) ? 22 : g - 233);
                        out[(size_t)b * length + p] = v[reg] * NR[grow * 1024 + ncol];
                    }
                }
            }
        }
    }
}

// Last-resort fallback (ws too small): on-the-fly trig gather.
__global__ void icqt_gather_fallback(const float* __restrict__ X, float* __restrict__ out,
                                     CqtArgs a, int length) {
    const int p = blockIdx.x * blockDim.x + threadIdx.x;
    if (p >= length) return;
    float acc[NB];
#pragma unroll
    for (int b = 0; b < NB; ++b) acc[b] = 0.0f;
    float nrm = 0.0f;
    int fhi = p >> 10;
    if (fhi > NFRAMES - 1) fhi = NFRAMES - 1;
    const float2* X2 = reinterpret_cast<const float2*>(X);
    for (int k = 0; k < NBINS; ++k) {
        const int L = a.wl[k];
        int flo = (p - L + HOP) >> 10;
        if (flo < 0) flo = 0;
        for (int f = flo; f <= fhi; ++f) {
            const int t = p - (f << 10);
            if (t < L) {
                float tf = (float)t;
                float ang = a.omega[k] * tf;
                float s = sinf(ang), c = cosf(ang);
                float w = 0.5f - 0.5f * cosf(6.28318530717958647692f * tf * a.invL[k]);
                float bre = c * w, bim = s * w;
                nrm += w * w;
                const int base = k * NFRAMES + f;
#pragma unroll
                for (int b = 0; b < NB; ++b) {
                    float2 cv = X2[(size_t)b * (NBINS * NFRAMES) + base];
                    acc[b] += cv.x * bre - cv.y * bim;
                }
            }
        }
    }
    const float inv = 1.0f / ((nrm > 1e-10f) ? nrm : 1.0f);
#pragma unroll
    for (int b = 0; b < NB; ++b)
        out[(size_t)b * length + p] = acc[b] * inv;
}

extern "C" void kernel_launch(void* const* d_in, const int* in_sizes, int n_in,
                              void* d_out, int out_size, void* d_ws, size_t ws_size,
                              hipStream_t stream) {
    // Host geometry (deterministic; np.round = banker's via nearbyint)
    CqtArgs a;
    const double SR = 44100.0;
    const double Q  = 1.0 / (std::exp2(1.0 / 12.0) - 1.0);
    int Ktot = 0;
    for (int k = 0; k < NBINS; ++k) {
        double f = 32.7 * std::exp2((double)k / 12.0);
        int L = (int)std::nearbyint(Q * SR / f);
        a.wl[k]    = L;
        a.cb[k]    = Ktot;
        a.omega[k] = (float)(2.0 * 3.14159265358979323846 * f / SR);
        a.invL[k]  = (float)(1.0 / (double)L);
        Ktot += 2 * ((L + 1023) / 1024);
    }
    a.Ktot = Ktot;

    const int length = out_size / NB;            // 283800
    const float* X = (const float*)d_in[0];
    float* out     = (float*)d_out;

    // ws layout (all 16B-aligned by construction)
    const size_t offA  = 0;
    const size_t szA   = (size_t)MPAD * KP * 2;          // 4,300,800
    const size_t offB  = offA + szA;
    const size_t szB   = (size_t)1024 * KP * 2;          // 1,966,080
    const size_t offNR = offB + szB;
    const size_t szNR  = (size_t)NRROWS * 1024 * 4;      //   184,320
    const size_t offCT = offNR + szNR;
    const size_t need  = offCT + (size_t)KP * 4;

    if (Ktot > KP || ws_size < need) {
        const int blocks = (length + 255) / 256;
        icqt_gather_fallback<<<blocks, 256, 0, stream>>>(X, out, a, length);
        return;
    }

    unsigned short* Am = (unsigned short*)((char*)d_ws + offA);
    unsigned short* Bt = (unsigned short*)((char*)d_ws + offB);
    float*          NR = (float*)((char*)d_ws + offNR);
    int*            CT = (int*)((char*)d_ws + offCT);

    build_coltab<<<dim3((KP + 255) / 256), 256, 0, stream>>>(CT, a);
    build_Bt<<<dim3((KP + 255) / 256, 1024), 256, 0, stream>>>(Bt, CT, a);
    build_A<<<dim3((KP + 255) / 256, MPAD), 256, 0, stream>>>(Am, X, CT, a);
    build_normrows<<<dim3(4, NRROWS), 256, 0, stream>>>(NR, a);
    gemm_icqt<<<dim3(MPAD / 64, 1024 / 64), 256, 0, stream>>>(Am, Bt, NR, out, length);
}

// Round 5
// 69.976 us; speedup vs baseline: 2.0024x; 2.0024x over previous
//
#include <hip/hip_runtime.h>
#include <hip/hip_fp16.h>
#include <cmath>

#define NBINS   84
#define NFRAMES 256
#define HOP     1024
#define NB      8            // nb_samples * nb_channels
#define KP      960          // padded K (columns of A / rows of B)
#define GBLK    278          // number of 1024-sample output blocks
#define MROWS   (GBLK*NB)    // 2224 real rows
#define MPAD    2240         // 35*64
#define NRROWS  45           // distinct norm rows: g in [0,22) | interior | (255,278)

typedef _Float16 f16x8 __attribute__((ext_vector_type(8)));
typedef float    f32x4 __attribute__((ext_vector_type(4)));

struct CqtArgs {
    int   wl[NBINS];     // per-bin window length
    int   cb[NBINS];     // column base: prefix sum of 2*ceil(wl/1024)
    float omega[NBINS];  // 2*pi*f/SR
    float invL[NBINS];   // 1/wl
    int   Ktot;
};

// col -> (k, d, c) lookup table; rec = k | d<<8 | c<<16, k=0xFF invalid/pad
__global__ void build_coltab(int* __restrict__ ct, CqtArgs a) {
    int col = blockIdx.x * 256 + threadIdx.x;
    if (col >= KP) return;
    int rec = 0xFF;
    if (col < a.Ktot) {
        for (int k = 0; k < NBINS; ++k) {
            int D2 = (((a.wl[k] + 1023) >> 10) << 1);
            int j  = col - a.cb[k];
            if (j >= 0 && j < D2) { rec = k | ((j >> 1) << 8) | ((j & 1) << 16); break; }
        }
    }
    ct[col] = rec;
}

// Bt[r][col] = (c ? sin : cos)(omega_k * t) * hann(t),  t = 1024 d + r, 0 if t >= L
__global__ void build_Bt(unsigned short* __restrict__ Bt, const int* __restrict__ ct,
                         CqtArgs a) {
    int col = blockIdx.x * 256 + threadIdx.x;
    int r   = blockIdx.y;
    if (col >= KP) return;
    float val = 0.f;
    int rec = ct[col];
    int k = rec & 0xFF;
    if (k != 0xFF) {
        int d = (rec >> 8) & 0xFF, c = rec >> 16;
        int t = (d << 10) + r;
        if (t < a.wl[k]) {
            float tf  = (float)t;
            float w   = 0.5f - 0.5f * cosf(6.28318530717958647692f * tf * a.invL[k]);
            float ang = a.omega[k] * tf;
            val = (c ? sinf(ang) : cosf(ang)) * w;
        }
    }
    Bt[(size_t)r * KP + col] = __half_as_ushort(__float2half(val));
}

// A[row=(g*8+b)][col=(k,d,c)] = c==0 ? Re X[b,k,g-d] : -Im X[b,k,g-d]; 0 OOB/pad
__global__ void build_A(unsigned short* __restrict__ Am, const float* __restrict__ X,
                        const int* __restrict__ ct, CqtArgs a) {
    int col = blockIdx.x * 256 + threadIdx.x;
    int row = blockIdx.y;
    if (col >= KP) return;
    float val = 0.f;
    int rec = ct[col];
    int k = rec & 0xFF;
    if (row < MROWS && k != 0xFF) {
        int d = (rec >> 8) & 0xFF, c = rec >> 16;
        int g = row >> 3, b = row & 7;
        int f = g - d;
        if (f >= 0 && f < NFRAMES) {
            float x = X[(((size_t)b * NBINS + k) * NFRAMES + f) * 2 + c];
            val = c ? -x : x;
        }
    }
    Am[(size_t)row * KP + col] = __half_as_ushort(__float2half(val));
}

// 45 distinct inverse-norm rows. ONE WAVE per (grow, r): lane strides the ~434
// cos-columns (8 iters, 1 cosf each), then 6-step butterfly reduce.
__global__ __launch_bounds__(256)
void norm_reduce(float* __restrict__ NR, const int* __restrict__ ct, CqtArgs a) {
    const int w = blockIdx.x * 4 + (threadIdx.x >> 6);    // wave id = (grow, r)
    const int l = threadIdx.x & 63;
    if (w >= NRROWS * 1024) return;
    const int grow = w >> 10;
    const int r    = w & 1023;
    const int g    = grow < 22 ? grow : (grow == 22 ? 128 : 233 + grow);

    float sum = 0.f;
    for (int j = l; j < KP / 2; j += 64) {                // cos-cols sit at even index
        const int rec = ct[2 * j];
        const int k   = rec & 0xFF;
        if (k == 0xFF) continue;
        const int d = (rec >> 8) & 0xFF;
        const int f = g - d;
        if (f < 0 || f >= NFRAMES) continue;
        const int t = (d << 10) + r;
        if (t < a.wl[k]) {
            float wv = 0.5f - 0.5f * cosf(6.28318530717958647692f * (float)t * a.invL[k]);
            sum += wv * wv;
        }
    }
#pragma unroll
    for (int off = 32; off; off >>= 1) sum += __shfl_xor(sum, off, 64);
    if (l == 0) NR[w] = (sum > 1e-10f) ? (1.0f / sum) : 1.0f;
}

// GEMM: C[M=2240][N=1024] = A[M][K=960] * Bt[N][K]^T, f16 in / f32 acc.
// 64x64 tile, 4 waves (2x2), each wave 32x32 via 2x2 mfma_f32_16x16x32_f16.
// LDS [row][kchunk] with chunk-XOR swizzle (T2); next-K global loads overlap MFMA.
__global__ __launch_bounds__(256)
void gemm_icqt(const unsigned short* __restrict__ Am, const unsigned short* __restrict__ Bt,
               const float* __restrict__ NR, float* __restrict__ out, int length) {
    __shared__ __align__(16) char lds[16384];
    const int tid = threadIdx.x;
    const int l   = tid & 63;
    const int wid = tid >> 6;
    const int wm  = wid >> 1, wn = wid & 1;
    const int bm  = blockIdx.x, bn = blockIdx.y;

    // staging: 512 16B-chunks per 64x64 f16 tile; thread covers q0=tid, q1=tid+256
    const int q0 = tid,      q1 = tid + 256;
    const int r0 = q0 >> 3,  c0 = q0 & 7, s0 = c0 ^ (r0 & 7);
    const int r1 = q1 >> 3,  c1 = q1 & 7, s1 = c1 ^ (r1 & 7);

    const char* gA = (const char*)Am + (size_t)(bm * 64) * KP * 2;
    const char* gB = (const char*)Bt + (size_t)(bn * 64) * KP * 2;
    const char* gA0 = gA + ((size_t)r0 * KP + s0 * 8) * 2;
    const char* gA1 = gA + ((size_t)r1 * KP + s1 * 8) * 2;
    const char* gB0 = gB + ((size_t)r0 * KP + s0 * 8) * 2;
    const char* gB1 = gB + ((size_t)r1 * KP + s1 * 8) * 2;
    char* lA = lds;
    char* lB = lds + 8192;

    f32x4 acc00 = {0.f,0.f,0.f,0.f}, acc01 = {0.f,0.f,0.f,0.f};
    f32x4 acc10 = {0.f,0.f,0.f,0.f}, acc11 = {0.f,0.f,0.f,0.f};

    f16x8 ra0 = *(const f16x8*)(gA0);
    f16x8 ra1 = *(const f16x8*)(gA1);
    f16x8 rb0 = *(const f16x8*)(gB0);
    f16x8 rb1 = *(const f16x8*)(gB1);

    const int arow0 = wm * 32 + (l & 15), arow1 = arow0 + 16;
    const int brow0 = wn * 32 + (l & 15), brow1 = brow0 + 16;
    const int kq = l >> 4;   // 0..3: k-chunk sub-index

    for (int kk = 0; kk < KP; kk += 64) {
        __syncthreads();                     // previous frag reads complete
        *(f16x8*)(lA + q0 * 16) = ra0;
        *(f16x8*)(lA + q1 * 16) = ra1;
        *(f16x8*)(lB + q0 * 16) = rb0;
        *(f16x8*)(lB + q1 * 16) = rb1;
        __syncthreads();
        if (kk + 64 < KP) {                  // prefetch next K-panel (overlaps MFMA)
            ra0 = *(const f16x8*)(gA0 + (kk + 64) * 2);
            ra1 = *(const f16x8*)(gA1 + (kk + 64) * 2);
            rb0 = *(const f16x8*)(gB0 + (kk + 64) * 2);
            rb1 = *(const f16x8*)(gB1 + (kk + 64) * 2);
        }
#pragma unroll
        for (int ks = 0; ks < 2; ++ks) {
            const int kb = ks * 4 + kq;      // chunk 0..7 within row
            f16x8 a0 = *(const f16x8*)(lA + arow0 * 128 + ((kb ^ (arow0 & 7)) << 4));
            f16x8 a1 = *(const f16x8*)(lA + arow1 * 128 + ((kb ^ (arow1 & 7)) << 4));
            f16x8 b0 = *(const f16x8*)(lB + brow0 * 128 + ((kb ^ (brow0 & 7)) << 4));
            f16x8 b1 = *(const f16x8*)(lB + brow1 * 128 + ((kb ^ (brow1 & 7)) << 4));
            acc00 = __builtin_amdgcn_mfma_f32_16x16x32_f16(a0, b0, acc00, 0, 0, 0);
            acc01 = __builtin_amdgcn_mfma_f32_16x16x32_f16(a0, b1, acc01, 0, 0, 0);
            acc10 = __builtin_amdgcn_mfma_f32_16x16x32_f16(a1, b0, acc10, 0, 0, 0);
            acc11 = __builtin_amdgcn_mfma_f32_16x16x32_f16(a1, b1, acc11, 0, 0, 0);
        }
    }

    // epilogue: C/D layout col=l&15, row=(l>>4)*4+reg; divide by norm, scatter to out
    const int mbase = bm * 64 + wm * 32;
    const int nbase = bn * 64 + wn * 32;
#pragma unroll
    for (int mi = 0; mi < 2; ++mi) {
#pragma unroll
        for (int ni = 0; ni < 2; ++ni) {
            f32x4 v = (mi == 0) ? ((ni == 0) ? acc00 : acc01)
                                : ((ni == 0) ? acc10 : acc11);
            const int ncol = nbase + ni * 16 + (l & 15);
#pragma unroll
            for (int reg = 0; reg < 4; ++reg) {
                const int mrow = mbase + mi * 16 + (l >> 4) * 4 + reg;
                if (mrow < MROWS) {
                    const int g = mrow >> 3, b = mrow & 7;
                    const int p = (g << 10) + ncol;
                    if (p < length) {
                        const int grow = (g < 22) ? g : ((g <= 255) ? 22 : g - 233);
                        out[(size_t)b * length + p] = v[reg] * NR[grow * 1024 + ncol];
                    }
                }
            }
        }
    }
}

// Last-resort fallback (ws too small): on-the-fly trig gather.
__global__ void icqt_gather_fallback(const float* __restrict__ X, float* __restrict__ out,
                                     CqtArgs a, int length) {
    const int p = blockIdx.x * blockDim.x + threadIdx.x;
    if (p >= length) return;
    float acc[NB];
#pragma unroll
    for (int b = 0; b < NB; ++b) acc[b] = 0.0f;
    float nrm = 0.0f;
    int fhi = p >> 10;
    if (fhi > NFRAMES - 1) fhi = NFRAMES - 1;
    const float2* X2 = reinterpret_cast<const float2*>(X);
    for (int k = 0; k < NBINS; ++k) {
        const int L = a.wl[k];
        int flo = (p - L + HOP) >> 10;
        if (flo < 0) flo = 0;
        for (int f = flo; f <= fhi; ++f) {
            const int t = p - (f << 10);
            if (t < L) {
                float tf = (float)t;
                float ang = a.omega[k] * tf;
                float s = sinf(ang), c = cosf(ang);
                float w = 0.5f - 0.5f * cosf(6.28318530717958647692f * tf * a.invL[k]);
                float bre = c * w, bim = s * w;
                nrm += w * w;
                const int base = k * NFRAMES + f;
#pragma unroll
                for (int b = 0; b < NB; ++b) {
                    float2 cv = X2[(size_t)b * (NBINS * NFRAMES) + base];
                    acc[b] += cv.x * bre - cv.y * bim;
                }
            }
        }
    }
    const float inv = 1.0f / ((nrm > 1e-10f) ? nrm : 1.0f);
#pragma unroll
    for (int b = 0; b < NB; ++b)
        out[(size_t)b * length + p] = acc[b] * inv;
}

extern "C" void kernel_launch(void* const* d_in, const int* in_sizes, int n_in,
                              void* d_out, int out_size, void* d_ws, size_t ws_size,
                              hipStream_t stream) {
    // Host geometry (deterministic; np.round = banker's via nearbyint)
    CqtArgs a;
    const double SR = 44100.0;
    const double Q  = 1.0 / (std::exp2(1.0 / 12.0) - 1.0);
    int Ktot = 0;
    for (int k = 0; k < NBINS; ++k) {
        double f = 32.7 * std::exp2((double)k / 12.0);
        int L = (int)std::nearbyint(Q * SR / f);
        a.wl[k]    = L;
        a.cb[k]    = Ktot;
        a.omega[k] = (float)(2.0 * 3.14159265358979323846 * f / SR);
        a.invL[k]  = (float)(1.0 / (double)L);
        Ktot += 2 * ((L + 1023) / 1024);
    }
    a.Ktot = Ktot;

    const int length = out_size / NB;            // 283800
    const float* X = (const float*)d_in[0];
    float* out     = (float*)d_out;

    // ws layout (all 16B-aligned by construction)
    const size_t offA  = 0;
    const size_t szA   = (size_t)MPAD * KP * 2;          // 4,300,800
    const size_t offB  = offA + szA;
    const size_t szB   = (size_t)1024 * KP * 2;          // 1,966,080
    const size_t offNR = offB + szB;
    const size_t szNR  = (size_t)NRROWS * 1024 * 4;      //   184,320
    const size_t offCT = offNR + szNR;
    const size_t need  = offCT + (size_t)KP * 4;

    if (Ktot > KP || ws_size < need) {
        const int blocks = (length + 255) / 256;
        icqt_gather_fallback<<<blocks, 256, 0, stream>>>(X, out, a, length);
        return;
    }

    unsigned short* Am = (unsigned short*)((char*)d_ws + offA);
    unsigned short* Bt = (unsigned short*)((char*)d_ws + offB);
    float*          NR = (float*)((char*)d_ws + offNR);
    int*            CT = (int*)((char*)d_ws + offCT);

    build_coltab<<<dim3((KP + 255) / 256), 256, 0, stream>>>(CT, a);
    build_Bt<<<dim3((KP + 255) / 256, 1024), 256, 0, stream>>>(Bt, CT, a);
    build_A<<<dim3((KP + 255) / 256, MPAD), 256, 0, stream>>>(Am, X, CT, a);
    norm_reduce<<<dim3(NRROWS * 1024 / 4), 256, 0, stream>>>(NR, CT, a);
    gemm_icqt<<<dim3(MPAD / 64, 1024 / 64), 256, 0, stream>>>(Am, Bt, NR, out, length);
}

// Round 6
// 52.620 us; speedup vs baseline: 2.6629x; 1.3298x over previous
//
#include <hip/hip_runtime.h>
#include <hip/hip_fp16.h>
#include <cmath>

#define NBINS   84
#define NFRAMES 256
#define HOP     1024
#define NB      8            // nb_samples * nb_channels
#define KP      960          // padded K (columns of A / rows of B)
#define GBLK    278          // number of 1024-sample output blocks
#define MROWS   (GBLK*NB)    // 2224 real rows
#define MPAD    2240         // 35*64
#define NRROWS  45           // distinct norm rows: g in [0,22) | interior(->22) | (255,278)

// mega_build region boundaries (blocks of 256 threads)
#define BT_BLOCKS   (4 * 1024)            // 4096: Bt[r][col]
#define A_BLOCKS    (4 * MPAD)            // 8960: A[row][col]
#define NORM_BLOCKS (NRROWS * 1024 / 4)   // 11520: one wave per (grow, r)
#define ALL_BLOCKS  (BT_BLOCKS + A_BLOCKS + NORM_BLOCKS)

typedef _Float16 f16x8 __attribute__((ext_vector_type(8)));
typedef float    f32x4 __attribute__((ext_vector_type(4)));

struct CqtArgs {
    int   wl[NBINS];            // per-bin window length
    float omega[NBINS];         // 2*pi*f/SR
    float invL[NBINS];          // 1/wl
    int   Ktot;
    unsigned short ct[KP];      // col -> k | d<<7 | c<<12 ; 0xFFFF = pad
};

// One fused builder: region 0 = Bt, region 1 = A, region 2 = norm rows.
// All regions independent; coltab lives in kernarg (host-computed).
__global__ __launch_bounds__(256)
void mega_build(unsigned short* __restrict__ Am, unsigned short* __restrict__ Bt,
                float* __restrict__ NR, const float* __restrict__ X, CqtArgs a) {
    const int blk = blockIdx.x;
    const int tid = threadIdx.x;
    const float TWOPI = 6.28318530717958647692f;

    if (blk < BT_BLOCKS) {
        // ---- Bt[r][col] = (c ? sin : cos)(omega_k * t) * hann(t), t = 1024 d + r
        const int col = (blk & 3) * 256 + tid;
        const int r   = blk >> 2;
        if (col >= KP) return;
        float val = 0.f;
        const unsigned short rec = a.ct[col];
        if (rec != 0xFFFF) {
            const int k = rec & 0x7F, d = (rec >> 7) & 0x1F, c = rec >> 12;
            const int t = (d << 10) + r;
            if (t < a.wl[k]) {
                const float tf = (float)t;
                const float w  = 0.5f - 0.5f * cosf(TWOPI * tf * a.invL[k]);
                float s, cc;
                sincosf(a.omega[k] * tf, &s, &cc);
                val = (c ? s : cc) * w;
            }
        }
        Bt[(size_t)r * KP + col] = __half_as_ushort(__float2half(val));
    } else if (blk < BT_BLOCKS + A_BLOCKS) {
        // ---- A[row=(g*8+b)][col=(k,d,c)] = c==0 ? Re X[b,k,g-d] : -Im X[b,k,g-d]
        const int idx = blk - BT_BLOCKS;
        const int col = (idx & 3) * 256 + tid;
        const int row = idx >> 2;
        if (col >= KP) return;
        float val = 0.f;
        const unsigned short rec = a.ct[col];
        if (row < MROWS && rec != 0xFFFF) {
            const int k = rec & 0x7F, d = (rec >> 7) & 0x1F, c = rec >> 12;
            const int g = row >> 3, b = row & 7;
            const int f = g - d;
            if (f >= 0 && f < NFRAMES) {
                const float x = X[(((size_t)b * NBINS + k) * NFRAMES + f) * 2 + c];
                val = c ? -x : x;
            }
        }
        Am[(size_t)row * KP + col] = __half_as_ushort(__float2half(val));
    } else {
        // ---- 45 distinct inverse-norm rows: one wave per (grow, r)
        const int idx = blk - BT_BLOCKS - A_BLOCKS;
        const int w   = idx * 4 + (tid >> 6);
        const int l   = tid & 63;
        if (w >= NRROWS * 1024) return;
        const int grow = w >> 10;
        const int r    = w & 1023;
        const int g    = grow < 22 ? grow : (grow == 22 ? 128 : 233 + grow);

        float sum = 0.f;
        for (int j = l; j < KP / 2; j += 64) {          // cos-cols sit at even index
            const unsigned short rec = a.ct[2 * j];
            if (rec == 0xFFFF) continue;
            const int k = rec & 0x7F, d = (rec >> 7) & 0x1F;
            const int f = g - d;
            if (f < 0 || f >= NFRAMES) continue;
            const int t = (d << 10) + r;
            if (t < a.wl[k]) {
                const float wv = 0.5f - 0.5f * cosf(TWOPI * (float)t * a.invL[k]);
                sum += wv * wv;
            }
        }
#pragma unroll
        for (int off = 32; off; off >>= 1) sum += __shfl_xor(sum, off, 64);
        if (l == 0) NR[w] = (sum > 1e-10f) ? (1.0f / sum) : 1.0f;
    }
}

// GEMM: C[M=2240][N=1024] = A[M][K=960] * Bt[N][K]^T, f16 in / f32 acc.
// 64x64 tile, 4 waves (2x2), each wave 32x32 via 2x2 mfma_f32_16x16x32_f16.
// LDS [row][kchunk] with chunk-XOR swizzle (T2); next-K global loads overlap MFMA.
__global__ __launch_bounds__(256)
void gemm_icqt(const unsigned short* __restrict__ Am, const unsigned short* __restrict__ Bt,
               const float* __restrict__ NR, float* __restrict__ out, int length) {
    __shared__ __align__(16) char lds[16384];
    const int tid = threadIdx.x;
    const int l   = tid & 63;
    const int wid = tid >> 6;
    const int wm  = wid >> 1, wn = wid & 1;
    const int bm  = blockIdx.x, bn = blockIdx.y;

    // staging: 512 16B-chunks per 64x64 f16 tile; thread covers q0=tid, q1=tid+256
    const int q0 = tid,      q1 = tid + 256;
    const int r0 = q0 >> 3,  c0 = q0 & 7, s0 = c0 ^ (r0 & 7);
    const int r1 = q1 >> 3,  c1 = q1 & 7, s1 = c1 ^ (r1 & 7);

    const char* gA = (const char*)Am + (size_t)(bm * 64) * KP * 2;
    const char* gB = (const char*)Bt + (size_t)(bn * 64) * KP * 2;
    const char* gA0 = gA + ((size_t)r0 * KP + s0 * 8) * 2;
    const char* gA1 = gA + ((size_t)r1 * KP + s1 * 8) * 2;
    const char* gB0 = gB + ((size_t)r0 * KP + s0 * 8) * 2;
    const char* gB1 = gB + ((size_t)r1 * KP + s1 * 8) * 2;
    char* lA = lds;
    char* lB = lds + 8192;

    f32x4 acc00 = {0.f,0.f,0.f,0.f}, acc01 = {0.f,0.f,0.f,0.f};
    f32x4 acc10 = {0.f,0.f,0.f,0.f}, acc11 = {0.f,0.f,0.f,0.f};

    f16x8 ra0 = *(const f16x8*)(gA0);
    f16x8 ra1 = *(const f16x8*)(gA1);
    f16x8 rb0 = *(const f16x8*)(gB0);
    f16x8 rb1 = *(const f16x8*)(gB1);

    const int arow0 = wm * 32 + (l & 15), arow1 = arow0 + 16;
    const int brow0 = wn * 32 + (l & 15), brow1 = brow0 + 16;
    const int kq = l >> 4;   // 0..3: k-chunk sub-index

    for (int kk = 0; kk < KP; kk += 64) {
        __syncthreads();                     // previous frag reads complete
        *(f16x8*)(lA + q0 * 16) = ra0;
        *(f16x8*)(lA + q1 * 16) = ra1;
        *(f16x8*)(lB + q0 * 16) = rb0;
        *(f16x8*)(lB + q1 * 16) = rb1;
        __syncthreads();
        if (kk + 64 < KP) {                  // prefetch next K-panel (overlaps MFMA)
            ra0 = *(const f16x8*)(gA0 + (kk + 64) * 2);
            ra1 = *(const f16x8*)(gA1 + (kk + 64) * 2);
            rb0 = *(const f16x8*)(gB0 + (kk + 64) * 2);
            rb1 = *(const f16x8*)(gB1 + (kk + 64) * 2);
        }
#pragma unroll
        for (int ks = 0; ks < 2; ++ks) {
            const int kb = ks * 4 + kq;      // chunk 0..7 within row
            f16x8 a0 = *(const f16x8*)(lA + arow0 * 128 + ((kb ^ (arow0 & 7)) << 4));
            f16x8 a1 = *(const f16x8*)(lA + arow1 * 128 + ((kb ^ (arow1 & 7)) << 4));
            f16x8 b0 = *(const f16x8*)(lB + brow0 * 128 + ((kb ^ (brow0 & 7)) << 4));
            f16x8 b1 = *(const f16x8*)(lB + brow1 * 128 + ((kb ^ (brow1 & 7)) << 4));
            acc00 = __builtin_amdgcn_mfma_f32_16x16x32_f16(a0, b0, acc00, 0, 0, 0);
            acc01 = __builtin_amdgcn_mfma_f32_16x16x32_f16(a0, b1, acc01, 0, 0, 0);
            acc10 = __builtin_amdgcn_mfma_f32_16x16x32_f16(a1, b0, acc10, 0, 0, 0);
            acc11 = __builtin_amdgcn_mfma_f32_16x16x32_f16(a1, b1, acc11, 0, 0, 0);
        }
    }

    // epilogue: C/D layout col=l&15, row=(l>>4)*4+reg; divide by norm, scatter to out
    const int mbase = bm * 64 + wm * 32;
    const int nbase = bn * 64 + wn * 32;
#pragma unroll
    for (int mi = 0; mi < 2; ++mi) {
#pragma unroll
        for (int ni = 0; ni < 2; ++ni) {
            f32x4 v = (mi == 0) ? ((ni == 0) ? acc00 : acc01)
                                : ((ni == 0) ? acc10 : acc11);
            const int ncol = nbase + ni * 16 + (l & 15);
#pragma unroll
            for (int reg = 0; reg < 4; ++reg) {
                const int mrow = mbase + mi * 16 + (l >> 4) * 4 + reg;
                if (mrow < MROWS) {
                    const int g = mrow >> 3, b = mrow & 7;
                    const int p = (g << 10) + ncol;
                    if (p < length) {
                        const int grow = (g < 22) ? g : ((g <= 255) ? 22 : g - 233);
                        out[(size_t)b * length + p] = v[reg] * NR[grow * 1024 + ncol];
                    }
                }
            }
        }
    }
}

// Last-resort fallback (ws too small): on-the-fly trig gather.
__global__ void icqt_gather_fallback(const float* __restrict__ X, float* __restrict__ out,
                                     CqtArgs a, int length) {
    const int p = blockIdx.x * blockDim.x + threadIdx.x;
    if (p >= length) return;
    float acc[NB];
#pragma unroll
    for (int b = 0; b < NB; ++b) acc[b] = 0.0f;
    float nrm = 0.0f;
    int fhi = p >> 10;
    if (fhi > NFRAMES - 1) fhi = NFRAMES - 1;
    const float2* X2 = reinterpret_cast<const float2*>(X);
    for (int k = 0; k < NBINS; ++k) {
        const int L = a.wl[k];
        int flo = (p - L + HOP) >> 10;
        if (flo < 0) flo = 0;
        for (int f = flo; f <= fhi; ++f) {
            const int t = p - (f << 10);
            if (t < L) {
                float tf = (float)t;
                float ang = a.omega[k] * tf;
                float s = sinf(ang), c = cosf(ang);
                float w = 0.5f - 0.5f * cosf(6.28318530717958647692f * tf * a.invL[k]);
                float bre = c * w, bim = s * w;
                nrm += w * w;
                const int base = k * NFRAMES + f;
#pragma unroll
                for (int b = 0; b < NB; ++b) {
                    float2 cv = X2[(size_t)b * (NBINS * NFRAMES) + base];
                    acc[b] += cv.x * bre - cv.y * bim;
                }
            }
        }
    }
    const float inv = 1.0f / ((nrm > 1e-10f) ? nrm : 1.0f);
#pragma unroll
    for (int b = 0; b < NB; ++b)
        out[(size_t)b * length + p] = acc[b] * inv;
}

extern "C" void kernel_launch(void* const* d_in, const int* in_sizes, int n_in,
                              void* d_out, int out_size, void* d_ws, size_t ws_size,
                              hipStream_t stream) {
    // Host geometry (deterministic; np.round = banker's via nearbyint)
    CqtArgs a;
    int cb[NBINS];
    const double SR = 44100.0;
    const double Q  = 1.0 / (std::exp2(1.0 / 12.0) - 1.0);
    int Ktot = 0;
    for (int k = 0; k < NBINS; ++k) {
        double f = 32.7 * std::exp2((double)k / 12.0);
        int L = (int)std::nearbyint(Q * SR / f);
        a.wl[k]    = L;
        cb[k]      = Ktot;
        a.omega[k] = (float)(2.0 * 3.14159265358979323846 * f / SR);
        a.invL[k]  = (float)(1.0 / (double)L);
        Ktot += 2 * ((L + 1023) / 1024);
    }
    a.Ktot = Ktot;
    // host-side coltab, compressed: k | d<<7 | c<<12, 0xFFFF = pad
    for (int col = 0; col < KP; ++col) a.ct[col] = 0xFFFF;
    if (Ktot <= KP) {
        for (int k = 0; k < NBINS; ++k) {
            const int D2 = 2 * ((a.wl[k] + 1023) / 1024);
            for (int j = 0; j < D2; ++j)
                a.ct[cb[k] + j] = (unsigned short)(k | ((j >> 1) << 7) | ((j & 1) << 12));
        }
    }

    const int length = out_size / NB;            // 283800
    const float* X = (const float*)d_in[0];
    float* out     = (float*)d_out;

    // ws layout (all 16B-aligned by construction)
    const size_t offA  = 0;
    const size_t szA   = (size_t)MPAD * KP * 2;          // 4,300,800
    const size_t offB  = offA + szA;
    const size_t szB   = (size_t)1024 * KP * 2;          // 1,966,080
    const size_t offNR = offB + szB;
    const size_t szNR  = (size_t)NRROWS * 1024 * 4;      //   184,320
    const size_t need  = offNR + szNR;

    if (Ktot > KP || ws_size < need) {
        const int blocks = (length + 255) / 256;
        icqt_gather_fallback<<<blocks, 256, 0, stream>>>(X, out, a, length);
        return;
    }

    unsigned short* Am = (unsigned short*)((char*)d_ws + offA);
    unsigned short* Bt = (unsigned short*)((char*)d_ws + offB);
    float*          NR = (float*)((char*)d_ws + offNR);

    mega_build<<<dim3(ALL_BLOCKS), 256, 0, stream>>>(Am, Bt, NR, X, a);
    gemm_icqt<<<dim3(MPAD / 64, 1024 / 64), 256, 0, stream>>>(Am, Bt, NR, out, length);
}